// Round 1
// baseline (57.250 us; speedup 1.0000x reference)
//
#include <hip/hip_runtime.h>
#include <math.h>

// Problem constants from the reference: B=8, C=3, H=64, W=64.
#define BB 8
#define CC 3
#define HH 64
#define WW 64
#define NN (HH * WW)

// The reference's dense tent-weight einsum is exactly 4-tap bilinear
// interpolation with zero padding: tent(d)=relu(1-|d|) has support width 2,
// so only floor(src) and floor(src)+1 get nonzero weight per axis.
__global__ __launch_bounds__(256) void rot_bilinear_kernel(
        const float* __restrict__ theta,   // [B,1]
        const float* __restrict__ image,   // [C,H,W]
        float* __restrict__ out) {         // [B,C,H,W]
    int tid = blockIdx.x * blockDim.x + threadIdx.x;
    if (tid >= BB * NN) return;

    int b  = tid >> 12;          // tid / 4096
    int n  = tid & (NN - 1);
    int gy = n >> 6;             // n / 64
    int gx = n & (WW - 1);

    const float c_x = (WW - 1) * 0.5f;
    const float c_y = (HH - 1) * 0.5f;

    float t = theta[b];
    float s, c;
    sincosf(t, &s, &c);          // precise variant (not __sincosf)

    float x_rel = (float)gx - c_x;
    float y_rel = (float)gy - c_y;
    float src_x = fmaf(c, x_rel, fmaf(s, y_rel, c_x));
    float src_y = fmaf(-s, x_rel, fmaf(c, y_rel, c_y));

    float fx = floorf(src_x);
    float fy = floorf(src_y);
    int x0 = (int)fx;
    int y0 = (int)fy;
    float ax = src_x - fx;       // weight of x0+1
    float ay = src_y - fy;       // weight of y0+1

    float w00 = (1.0f - ay) * (1.0f - ax);
    float w01 = (1.0f - ay) * ax;
    float w10 = ay * (1.0f - ax);
    float w11 = ay * ax;

    bool vx0 = (unsigned)x0       < (unsigned)WW;
    bool vx1 = (unsigned)(x0 + 1) < (unsigned)WW;
    bool vy0 = (unsigned)y0       < (unsigned)HH;
    bool vy1 = (unsigned)(y0 + 1) < (unsigned)HH;

    int i00 = y0 * WW + x0;      // only dereferenced when valid

    #pragma unroll
    for (int ch = 0; ch < CC; ++ch) {
        const float* img = image + ch * NN;
        float v = 0.0f;
        if (vy0 && vx0) v = fmaf(w00, img[i00],          v);
        if (vy0 && vx1) v = fmaf(w01, img[i00 + 1],      v);
        if (vy1 && vx0) v = fmaf(w10, img[i00 + WW],     v);
        if (vy1 && vx1) v = fmaf(w11, img[i00 + WW + 1], v);
        out[((b * CC + ch) * HH + gy) * WW + gx] = v;
    }
}

extern "C" void kernel_launch(void* const* d_in, const int* in_sizes, int n_in,
                              void* d_out, int out_size, void* d_ws, size_t ws_size,
                              hipStream_t stream) {
    const float* theta = (const float*)d_in[0];  // [B,1] fp32
    const float* image = (const float*)d_in[1];  // [C,H,W] fp32
    float* out = (float*)d_out;                  // [B,C,H,W] fp32

    const int total = BB * NN;                   // one thread per (b, gy, gx)
    const int block = 256;
    const int grid  = (total + block - 1) / block;
    rot_bilinear_kernel<<<grid, block, 0, stream>>>(theta, image, out);
}

// Round 2
// 55.519 us; speedup vs baseline: 1.0312x; 1.0312x over previous
//
#include <hip/hip_runtime.h>
#include <math.h>

// Problem constants from the reference: B=8, C=3, H=64, W=64.
#define BB 8
#define CC 3
#define HH 64
#define WW 64
#define NN (HH * WW)

// The reference's dense tent-weight einsum is exactly 4-tap bilinear
// interpolation with zero padding: tent(d)=relu(1-|d|) has support width 2,
// so only floor(src) and floor(src)+1 get nonzero weight per axis.
//
// R2 changes vs R1:
//  - __sincosf (hw v_sin/v_cos): theta ~ N(0,1), accuracy margin is 8.5x.
//  - branchless taps: clamp indices into [0,63], zero the weights of
//    out-of-range taps. All 12 loads issue unconditionally -> one vmcnt
//    wait, no exec-mask divergence at image edges.
__global__ __launch_bounds__(256) void rot_bilinear_kernel(
        const float* __restrict__ theta,   // [B,1]
        const float* __restrict__ image,   // [C,H,W]
        float* __restrict__ out) {         // [B,C,H,W]
    int tid = blockIdx.x * blockDim.x + threadIdx.x;
    if (tid >= BB * NN) return;

    int b  = tid >> 12;          // tid / 4096
    int n  = tid & (NN - 1);
    int gy = n >> 6;             // n / 64
    int gx = n & (WW - 1);

    const float c_x = (WW - 1) * 0.5f;
    const float c_y = (HH - 1) * 0.5f;

    float t = theta[b];
    float s, c;
    __sincosf(t, &s, &c);        // fast hw path; plenty of accuracy margin

    float x_rel = (float)gx - c_x;
    float y_rel = (float)gy - c_y;
    float src_x = fmaf(c, x_rel, fmaf(s, y_rel, c_x));
    float src_y = fmaf(-s, x_rel, fmaf(c, y_rel, c_y));

    float fx = floorf(src_x);
    float fy = floorf(src_y);
    int x0 = (int)fx;
    int y0 = (int)fy;
    float ax = src_x - fx;       // weight of x0+1
    float ay = src_y - fy;       // weight of y0+1
    float bx = 1.0f - ax;
    float by = 1.0f - ay;

    // Zero-padding: out-of-range taps get weight 0; indices clamped so the
    // loads are always in-bounds (value then multiplied by 0).
    bool vx0 = (unsigned)x0       < (unsigned)WW;
    bool vx1 = (unsigned)(x0 + 1) < (unsigned)WW;
    bool vy0 = (unsigned)y0       < (unsigned)HH;
    bool vy1 = (unsigned)(y0 + 1) < (unsigned)HH;
    float wx0 = vx0 ? bx : 0.0f;
    float wx1 = vx1 ? ax : 0.0f;
    float wy0 = vy0 ? by : 0.0f;
    float wy1 = vy1 ? ay : 0.0f;
    float w00 = wy0 * wx0;
    float w01 = wy0 * wx1;
    float w10 = wy1 * wx0;
    float w11 = wy1 * wx1;

    int x0c = min(max(x0, 0), WW - 1);
    int x1c = min(max(x0 + 1, 0), WW - 1);
    int y0c = min(max(y0, 0), HH - 1);
    int y1c = min(max(y0 + 1, 0), HH - 1);
    int i00 = y0c * WW + x0c;
    int i01 = y0c * WW + x1c;
    int i10 = y1c * WW + x0c;
    int i11 = y1c * WW + x1c;

    const float* img = image;
    float* o = out + b * CC * NN + n;
    #pragma unroll
    for (int ch = 0; ch < CC; ++ch, img += NN, o += NN) {
        float v = w00 * img[i00] + w01 * img[i01]
                + w10 * img[i10] + w11 * img[i11];
        *o = v;                  // wave writes 64 contiguous floats: coalesced
    }
}

extern "C" void kernel_launch(void* const* d_in, const int* in_sizes, int n_in,
                              void* d_out, int out_size, void* d_ws, size_t ws_size,
                              hipStream_t stream) {
    const float* theta = (const float*)d_in[0];  // [B,1] fp32
    const float* image = (const float*)d_in[1];  // [C,H,W] fp32
    float* out = (float*)d_out;                  // [B,C,H,W] fp32

    const int total = BB * NN;                   // one thread per (b, gy, gx)
    const int block = 256;
    const int grid  = (total + block - 1) / block;
    rot_bilinear_kernel<<<grid, block, 0, stream>>>(theta, image, out);
}